// Round 3
// baseline (223.187 us; speedup 1.0000x reference)
//
#include <hip/hip_runtime.h>
#include <math.h>

#define TSTEPS 200
#define NROTS  40      // 5*NQ*NL params per timestep circuit (2 layers)
#define BLK    128     // 2 waves; each thread simulates TWO timesteps (packed fp32)
#define DEG    3

// ---- packed float2 (maps to v_pk_*_f32 on gfx950) ----
typedef float v2 __attribute__((ext_vector_type(2)));

__device__ __forceinline__ v2 mk2(float a, float b) { v2 r; r.x = a; r.y = b; return r; }

#if __has_builtin(__builtin_elementwise_fma)
#define FMA2(a, b, c) __builtin_elementwise_fma((a), (b), (c))
#else
__device__ __forceinline__ v2 FMA2(v2 a, v2 b, v2 c) {
#pragma clang fp contract(fast)
    return a * b + c;
}
#endif

__device__ __forceinline__ v2 sin2(v2 h) { return mk2(__sinf(h.x), __sinf(h.y)); }
__device__ __forceinline__ v2 cos2(v2 h) { return mk2(__cosf(h.x), __cosf(h.y)); }

__device__ __forceinline__ void fsc(float h, float& s, float& c) {
    s = __sinf(h); c = __cosf(h);
}

// Fused U = RZ(h3)*RY(h2)*RX(h1); only u00,u01 needed (u11=conj(u00), u10=-conj(u01)).
// Algebra verified in earlier rounds; element-wise over the 2 timestep slots.
__device__ __forceinline__ void make_u2(v2 h1, v2 h2, v2 h3, v2* u) {
    v2 s1 = sin2(h1), c1 = cos2(h1);
    v2 s2 = sin2(h2), c2 = cos2(h2);
    v2 s3 = sin2(h3), c3 = cos2(h3);
    v2 A = c1 * c2, Bv = s1 * s2, C = c1 * s2, D = s1 * c2;
    u[0] = FMA2(s3, Bv, c3 * A);        //  c3*A + s3*Bv
    u[1] = FMA2(-s3, A, c3 * Bv);       //  c3*Bv - s3*A
    u[2] = -FMA2(s3, D, c3 * C);        // -(c3*C + s3*D)
    u[3] = FMA2(-c3, D, s3 * C);        //  s3*C - c3*D
}

__device__ __forceinline__ void fsc2(v2 h, v2* sc) { sc[0] = sin2(h); sc[1] = cos2(h); }

// Planar state: V[0..15] = real amps, V[16..31] = imag; each v2 packs 2 timesteps.
// Wire w <-> bit (8>>w). Gate formulas verified; explicit fma chains.
template<int BIT>
__device__ __forceinline__ void g_u2(v2* V, const v2* u) {
    const v2 u00r = u[0], u00i = u[1], u01r = u[2], u01i = u[3];
    #pragma unroll
    for (int p = 0; p < 16; ++p) {
        if (p & BIT) continue;
        const int q = p | BIT;
        v2 a0r = V[p], a0i = V[16 + p], a1r = V[q], a1i = V[16 + q];
        v2 t0 = u00r * a0r;
        t0 = FMA2(-u00i, a0i, t0);
        t0 = FMA2( u01r, a1r, t0);
        t0 = FMA2(-u01i, a1i, t0);
        v2 t1 = u00r * a0i;
        t1 = FMA2( u00i, a0r, t1);
        t1 = FMA2( u01r, a1i, t1);
        t1 = FMA2( u01i, a1r, t1);
        v2 t2 = u00r * a1r;
        t2 = FMA2( u00i, a1i, t2);
        t2 = FMA2(-u01r, a0r, t2);
        t2 = FMA2(-u01i, a0i, t2);
        v2 t3 = u00r * a1i;
        t3 = FMA2(-u00i, a1r, t3);
        t3 = FMA2(-u01r, a0i, t3);
        t3 = FMA2( u01i, a0r, t3);
        V[p] = t0; V[16 + p] = t1; V[q] = t2; V[16 + q] = t3;
    }
}

template<int CBIT, int TBIT>
__device__ __forceinline__ void g_crx_pre(v2* V, v2 s, v2 c) {
    #pragma unroll
    for (int p = 0; p < 16; ++p) {
        if (!(p & CBIT) || (p & TBIT)) continue;   // control=1, target=0 rows
        const int q = p | TBIT;
        v2 a0r = V[p], a0i = V[16 + p], a1r = V[q], a1i = V[16 + q];
        V[p]      = FMA2( s, a1i, c * a0r);
        V[16 + p] = FMA2(-s, a1r, c * a0i);
        V[q]      = FMA2( s, a0i, c * a1r);
        V[16 + q] = FMA2(-s, a0r, c * a1i);
    }
}

// Reduce-scatter halving step (scalar; slots already summed).
template<int S, int HALF>
__device__ __forceinline__ void rstep(float* V, int lane) {
    const bool hi = (lane >> S) & 1;
    #pragma unroll
    for (int j = 0; j < HALF; ++j) {
        float send = hi ? V[j] : V[j + HALF];
        float keep = hi ? V[j + HALF] : V[j];
        V[j] = keep + __shfl_xor(send, 1 << S, 64);
    }
}

// One full QSVT pass. __noinline__ is the point: it makes it impossible for
// LICM/GVN to hoist the (loop-invariant) param loads + trig across passes,
// which is what blew register pressure and triggered remat bloat in rounds 0-1.
// Everything here is transient: peak live set ~ V(64) + one load group(24-32)
// + u/sc(8) + temps -> fits the 128-VGPR / 4-waves-per-SIMD budget natively.
__device__ __noinline__ void qsvt_pass(
    const float4* __restrict__ p4A, const float4* __restrict__ p4B,
    v2 cr_, v2 ci_, float pk, int tid, int lane, int wv, int vidx,
    float* __restrict__ s_w, float (* __restrict__ s_red)[32],
    float* __restrict__ s_acc)
{
    v2 V[32];
    #pragma unroll
    for (int i = 0; i < 32; ++i) { float t = s_w[i]; V[i] = mk2(t, t); }

    #pragma unroll
    for (int L = 0; L < 2; ++L) {
        // load group 1: rotation-gate params (24 floats live)
        const float4 a0 = p4A[5*L+0], a1 = p4A[5*L+1], a2 = p4A[5*L+2];
        const float4 b0 = p4B[5*L+0], b1 = p4B[5*L+1], b2 = p4B[5*L+2];
        v2 u[4];
        make_u2(mk2(0.5f*a0.x, 0.5f*b0.x), mk2(0.5f*a0.y, 0.5f*b0.y), mk2(0.5f*a0.z, 0.5f*b0.z), u);
        g_u2<8>(V, u);
        make_u2(mk2(0.5f*a0.w, 0.5f*b0.w), mk2(0.5f*a1.x, 0.5f*b1.x), mk2(0.5f*a1.y, 0.5f*b1.y), u);
        g_u2<4>(V, u);
        make_u2(mk2(0.5f*a1.z, 0.5f*b1.z), mk2(0.5f*a1.w, 0.5f*b1.w), mk2(0.5f*a2.x, 0.5f*b2.x), u);
        g_u2<2>(V, u);
        make_u2(mk2(0.5f*a2.y, 0.5f*b2.y), mk2(0.5f*a2.z, 0.5f*b2.z), mk2(0.5f*a2.w, 0.5f*b2.w), u);
        g_u2<1>(V, u);
        // load group 2: CRX params (16 floats live)
        const float4 a3 = p4A[5*L+3], a4 = p4A[5*L+4];
        const float4 b3 = p4B[5*L+3], b4 = p4B[5*L+4];
        v2 sc[2];
        fsc2(mk2(0.5f*a3.x, 0.5f*b3.x), sc); g_crx_pre<8, 4>(V, sc[0], sc[1]);
        fsc2(mk2(0.5f*a3.y, 0.5f*b3.y), sc); g_crx_pre<4, 2>(V, sc[0], sc[1]);
        fsc2(mk2(0.5f*a3.z, 0.5f*b3.z), sc); g_crx_pre<2, 1>(V, sc[0], sc[1]);
        fsc2(mk2(0.5f*a3.w, 0.5f*b3.w), sc); g_crx_pre<1, 8>(V, sc[0], sc[1]);
        fsc2(mk2(0.5f*a4.x, 0.5f*b4.x), sc); g_crx_pre<1, 2>(V, sc[0], sc[1]);
        fsc2(mk2(0.5f*a4.y, 0.5f*b4.y), sc); g_crx_pre<2, 4>(V, sc[0], sc[1]);
        fsc2(mk2(0.5f*a4.z, 0.5f*b4.z), sc); g_crx_pre<4, 8>(V, sc[0], sc[1]);
        fsc2(mk2(0.5f*a4.w, 0.5f*b4.w), sc); g_crx_pre<8, 1>(V, sc[0], sc[1]);
    }

    // scale by each slot's LCU coefficient (0 for dead slot-B lanes)
    #pragma unroll
    for (int i = 0; i < 16; ++i) {
        v2 r = V[i], im = V[16 + i];
        V[i]      = FMA2(-im, ci_, r * cr_);
        V[16 + i] = FMA2( im, cr_, r * ci_);
    }

    // collapse the two timestep slots, then reduce across lanes
    float S[32];
    #pragma unroll
    for (int i = 0; i < 32; ++i) S[i] = V[i].x + V[i].y;

    rstep<0, 16>(S, lane);
    rstep<1, 8>(S, lane);
    rstep<2, 4>(S, lane);
    rstep<3, 2>(S, lane);
    rstep<4, 1>(S, lane);
    float tot = S[0] + __shfl_xor(S[0], 32, 64);
    if (lane < 32) s_red[wv][vidx] = tot;

    __syncthreads();
    if (tid < 32) {
        float r = s_red[0][tid] + s_red[1][tid];
        s_w[tid] = r;
        s_acc[tid] += pk * r;
    }
    __syncthreads();
}

// One block per batch element. Thread t simulates timesteps {t, t+128} packed.
// __launch_bounds__(128,4): cap VGPRs at 128 -> 4 waves/SIMD -> the full
// 4096-wave grid is resident (8 blocks/CU), fixing round-1's 17% occupancy.
extern "C" __global__ void __launch_bounds__(BLK, 4)
qac_kernel(const float* __restrict__ tp,    // (B, T, NROTS)
           const float* __restrict__ poly,  // (DEG+1,)
           const float* __restrict__ mixr,  // (T,)
           const float* __restrict__ mixi,  // (T,)
           const float* __restrict__ qff,   // (20,)
           float* __restrict__ out)         // (B, 12)
{
    __shared__ float s_red[2][32];   // per-wave reduced values (value-indexed)
    __shared__ float s_w[32];        // work vector  (0..15 re, 16..31 im)
    __shared__ float s_acc[32];      // QSVT accumulator, same layout

    const int b    = blockIdx.x;
    const int tid  = threadIdx.x;
    const int lane = tid & 63;
    const int wv   = tid >> 6;

    if (tid < 32) {
        s_w[tid]   = (tid == 0) ? 1.f : 0.f;
        s_acc[tid] = (tid == 0) ? poly[0] : 0.f;
    }

    // slot A = timestep tid (always < 200); slot B = timestep tid+128 (clamped, coeff 0)
    const bool vB = (tid + BLK) < TSTEPS;
    const int  tB = vB ? (tid + BLK) : (TSTEPS - 1);
    v2 cr_ = mk2(mixr[tid], vB ? mixr[tid + BLK] : 0.f);
    v2 ci_ = mk2(mixi[tid], vB ? mixi[tid + BLK] : 0.f);

    const float4* p4A = (const float4*)(tp + (size_t)b * (TSTEPS * NROTS) + tid * NROTS);
    const float4* p4B = (const float4*)(tp + (size_t)b * (TSTEPS * NROTS) + tB * NROTS);

    // reduce-scatter destination: value index bitrev5(lane&31) (verified round 2)
    const int vidx = ((lane & 1) << 4) | ((lane & 2) << 2) | (lane & 4) |
                     ((lane & 8) >> 2) | ((lane & 16) >> 4);

    __syncthreads();

    #pragma unroll 1
    for (int k = 1; k <= DEG; ++k) {
        qsvt_pass(p4A, p4B, cr_, ci_, poly[k], tid, lane, wv, vidx,
                  s_w, s_red, s_acc);
    }

    // ---- finalize on wave 0, lane-per-amplitude (verified round 2) ----
    if (tid < 16) {
        const int l = tid;
        float l1 = fabsf(poly[0]) + fabsf(poly[1]) + fabsf(poly[2]) + fabsf(poly[3]);
        float inv = 1.f / l1;
        float ar = s_acc[l] * inv, ai = s_acc[16 + l] * inv;
        float n2 = ar * ar + ai * ai;
        #pragma unroll
        for (int o = 1; o < 16; o <<= 1) n2 += __shfl_xor(n2, o, 64);
        float sc = 1.f / (sqrtf(n2) + 1e-9f);
        ar *= sc; ai *= sc;

        float s, c, pr, pi, se, ce, t0;
        #pragma unroll
        for (int w = 0; w < 4; ++w) {
            const int BIT = 8 >> w;
            fsc(0.5f * qff[3 * w + 0], s, c);            // RX
            pr = __shfl_xor(ar, BIT, 64); pi = __shfl_xor(ai, BIT, 64);
            t0 = c * ar + s * pi; ai = c * ai - s * pr; ar = t0;
            fsc(0.5f * qff[3 * w + 1], s, c);            // RY
            pr = __shfl_xor(ar, BIT, 64); pi = __shfl_xor(ai, BIT, 64);
            se = (l & BIT) ? s : -s;
            t0 = c * ar + se * pr; ai = c * ai + se * pi; ar = t0;
            fsc(0.5f * qff[3 * w + 2], s, c);            // RZ
            se = (l & BIT) ? s : -s;
            t0 = c * ar - se * ai; ai = c * ai + se * ar; ar = t0;
        }
        #define CRXF(CB, TB, hp) { fsc(0.5f * (hp), s, c);                        \
            pr = __shfl_xor(ar, TB, 64); pi = __shfl_xor(ai, TB, 64);             \
            ce = (l & CB) ? c : 1.f; se = (l & CB) ? s : 0.f;                     \
            t0 = ce * ar + se * pi; ai = ce * ai - se * pr; ar = t0; }
        CRXF(8, 4, qff[12]) CRXF(4, 2, qff[13]) CRXF(2, 1, qff[14]) CRXF(1, 8, qff[15])
        CRXF(1, 2, qff[16]) CRXF(2, 4, qff[17]) CRXF(4, 8, qff[18]) CRXF(8, 1, qff[19])
        #undef CRXF

        float* o = out + (size_t)b * 12;
        #pragma unroll
        for (int w = 0; w < 4; ++w) {
            const int BIT = 8 >> w;
            pr = __shfl_xor(ar, BIT, 64); pi = __shfl_xor(ai, BIT, 64);
            float m = (l & BIT) ? 0.f : 1.f;
            float X = m * 2.f * (ar * pr + ai * pi);
            float Y = m * 2.f * (ar * pi - ai * pr);
            float Z = m * (ar * ar + ai * ai - pr * pr - pi * pi);
            #pragma unroll
            for (int of = 1; of < 16; of <<= 1) {
                X += __shfl_xor(X, of, 64);
                Y += __shfl_xor(Y, of, 64);
                Z += __shfl_xor(Z, of, 64);
            }
            if (l == 0) { o[w] = X; o[4 + w] = Y; o[8 + w] = Z; }
        }
    }
}

extern "C" void kernel_launch(void* const* d_in, const int* in_sizes, int n_in,
                              void* d_out, int out_size, void* d_ws, size_t ws_size,
                              hipStream_t stream) {
    const float* tp   = (const float*)d_in[0];
    const float* poly = (const float*)d_in[1];
    const float* mixr = (const float*)d_in[2];
    const float* mixi = (const float*)d_in[3];
    const float* qff  = (const float*)d_in[4];
    float* out = (float*)d_out;
    const int B = in_sizes[0] / (TSTEPS * NROTS);   // 2048
    qac_kernel<<<dim3(B), dim3(BLK), 0, stream>>>(tp, poly, mixr, mixi, qff, out);
}

// Round 4
// 196.183 us; speedup vs baseline: 1.1376x; 1.1376x over previous
//
#include <hip/hip_runtime.h>
#include <math.h>

#define TSTEPS 200
#define NROTS  40      // 5*NQ*NL params per timestep circuit (2 layers)
#define BLK    128     // 2 waves; each thread simulates TWO timesteps (packed fp32)
#define DEG    3

// ---- packed float2 (maps to v_pk_*_f32 on gfx950) ----
typedef float v2 __attribute__((ext_vector_type(2)));

__device__ __forceinline__ v2 mk2(float a, float b) { v2 r; r.x = a; r.y = b; return r; }

#if __has_builtin(__builtin_elementwise_fma)
#define FMA2(a, b, c) __builtin_elementwise_fma((a), (b), (c))
#else
__device__ __forceinline__ v2 FMA2(v2 a, v2 b, v2 c) {
#pragma clang fp contract(fast)
    return a * b + c;
}
#endif

__device__ __forceinline__ v2 sin2(v2 h) { return mk2(__sinf(h.x), __sinf(h.y)); }
__device__ __forceinline__ v2 cos2(v2 h) { return mk2(__cosf(h.x), __cosf(h.y)); }

__device__ __forceinline__ void fsc(float h, float& s, float& c) {
    s = __sinf(h); c = __cosf(h);
}

// Fused U = RZ(h3)*RY(h2)*RX(h1); only u00,u01 needed (u11=conj(u00), u10=-conj(u01)).
// Algebra verified in earlier rounds; element-wise over the 2 timestep slots.
__device__ __forceinline__ void make_u2(v2 h1, v2 h2, v2 h3, v2* u) {
    v2 s1 = sin2(h1), c1 = cos2(h1);
    v2 s2 = sin2(h2), c2 = cos2(h2);
    v2 s3 = sin2(h3), c3 = cos2(h3);
    v2 A = c1 * c2, Bv = s1 * s2, C = c1 * s2, D = s1 * c2;
    u[0] = FMA2(s3, Bv, c3 * A);        //  c3*A + s3*Bv
    u[1] = FMA2(-s3, A, c3 * Bv);       //  c3*Bv - s3*A
    u[2] = -FMA2(s3, D, c3 * C);        // -(c3*C + s3*D)
    u[3] = FMA2(-c3, D, s3 * C);        //  s3*C - c3*D
}

__device__ __forceinline__ void fsc2(v2 h, v2* sc) { sc[0] = sin2(h); sc[1] = cos2(h); }

// Planar state: V[0..15] = real amps, V[16..31] = imag; each v2 packs 2 timesteps.
// Wire w <-> bit (8>>w). Gate formulas verified; explicit fma chains.
template<int BIT>
__device__ __forceinline__ void g_u2(v2* V, const v2* u) {
    const v2 u00r = u[0], u00i = u[1], u01r = u[2], u01i = u[3];
    #pragma unroll
    for (int p = 0; p < 16; ++p) {
        if (p & BIT) continue;
        const int q = p | BIT;
        v2 a0r = V[p], a0i = V[16 + p], a1r = V[q], a1i = V[16 + q];
        v2 t0 = u00r * a0r;
        t0 = FMA2(-u00i, a0i, t0);
        t0 = FMA2( u01r, a1r, t0);
        t0 = FMA2(-u01i, a1i, t0);
        v2 t1 = u00r * a0i;
        t1 = FMA2( u00i, a0r, t1);
        t1 = FMA2( u01r, a1i, t1);
        t1 = FMA2( u01i, a1r, t1);
        v2 t2 = u00r * a1r;
        t2 = FMA2( u00i, a1i, t2);
        t2 = FMA2(-u01r, a0r, t2);
        t2 = FMA2(-u01i, a0i, t2);
        v2 t3 = u00r * a1i;
        t3 = FMA2(-u00i, a1r, t3);
        t3 = FMA2(-u01r, a0i, t3);
        t3 = FMA2( u01i, a0r, t3);
        V[p] = t0; V[16 + p] = t1; V[q] = t2; V[16 + q] = t3;
    }
}

template<int CBIT, int TBIT>
__device__ __forceinline__ void g_crx_pre(v2* V, v2 s, v2 c) {
    #pragma unroll
    for (int p = 0; p < 16; ++p) {
        if (!(p & CBIT) || (p & TBIT)) continue;   // control=1, target=0 rows
        const int q = p | TBIT;
        v2 a0r = V[p], a0i = V[16 + p], a1r = V[q], a1i = V[16 + q];
        V[p]      = FMA2( s, a1i, c * a0r);
        V[16 + p] = FMA2(-s, a1r, c * a0i);
        V[q]      = FMA2( s, a0i, c * a1r);
        V[16 + q] = FMA2(-s, a0r, c * a1i);
    }
}

// Reduce-scatter halving step (scalar; slots already summed).
template<int S, int HALF>
__device__ __forceinline__ void rstep(float* V, int lane) {
    const bool hi = (lane >> S) & 1;
    #pragma unroll
    for (int j = 0; j < HALF; ++j) {
        float send = hi ? V[j] : V[j + HALF];
        float keep = hi ? V[j + HALF] : V[j];
        V[j] = keep + __shfl_xor(send, 1 << S, 64);
    }
}

// One block per batch element. Thread t simulates timesteps {t, t+128} packed.
// __launch_bounds__(128,4): VGPR cap 128 -> 4 waves/SIMD, full grid resident.
// All pass-local state (V, u, loaded params) is transient; the pointer launder
// in the k-loop prevents LICM/GVN from rebuilding round-1's hoisted trig
// tables (which blew pressure -> remat bloat). NO __noinline__ (round 3's
// callee-ABI scratch catastrophe: 148 MB spill writes).
extern "C" __global__ void __launch_bounds__(BLK, 4)
qac_kernel(const float* __restrict__ tp,    // (B, T, NROTS)
           const float* __restrict__ poly,  // (DEG+1,)
           const float* __restrict__ mixr,  // (T,)
           const float* __restrict__ mixi,  // (T,)
           const float* __restrict__ qff,   // (20,)
           float* __restrict__ out)         // (B, 12)
{
    __shared__ float s_red[2][32];   // per-wave reduced values (value-indexed)
    __shared__ float s_w[32];        // work vector  (0..15 re, 16..31 im)
    __shared__ float s_acc[32];      // QSVT accumulator, same layout

    const int b    = blockIdx.x;
    const int tid  = threadIdx.x;
    const int lane = tid & 63;
    const int wv   = tid >> 6;

    if (tid < 32) {
        s_w[tid]   = (tid == 0) ? 1.f : 0.f;
        s_acc[tid] = (tid == 0) ? poly[0] : 0.f;
    }

    // slot A = timestep tid (always < 200); slot B = timestep tid+128 (clamped, coeff 0)
    const bool vB = (tid + BLK) < TSTEPS;
    const int  tB = vB ? (tid + BLK) : (TSTEPS - 1);
    v2 cr_ = mk2(mixr[tid], vB ? mixr[tid + BLK] : 0.f);
    v2 ci_ = mk2(mixi[tid], vB ? mixi[tid + BLK] : 0.f);

    const float4* p4A = (const float4*)(tp + (size_t)b * (TSTEPS * NROTS) + tid * NROTS);
    const float4* p4B = (const float4*)(tp + (size_t)b * (TSTEPS * NROTS) + tB * NROTS);

    // reduce-scatter destination: value index bitrev5(lane&31) (verified round 2)
    const int vidx = ((lane & 1) << 4) | ((lane & 2) << 2) | (lane & 4) |
                     ((lane & 8) >> 2) | ((lane & 16) >> 4);

    __syncthreads();

    #pragma unroll 1
    for (int k = 1; k <= DEG; ++k) {
        // Launder the param pointers: compiler must treat them as fresh each
        // pass, so param loads (and the trig that depends on them) cannot be
        // hoisted/CSE'd out of the k-loop. Keeps live set ~110 VGPRs.
        asm volatile("" : "+v"(p4A), "+v"(p4B));

        v2 V[32];
        #pragma unroll
        for (int i = 0; i < 32; ++i) { float t = s_w[i]; V[i] = mk2(t, t); }

        #pragma unroll
        for (int L = 0; L < 2; ++L) {
            // load group 1: rotation-gate params (24 floats live)
            const float4 a0 = p4A[5*L+0], a1 = p4A[5*L+1], a2 = p4A[5*L+2];
            const float4 b0 = p4B[5*L+0], b1 = p4B[5*L+1], b2 = p4B[5*L+2];
            v2 u[4];
            make_u2(mk2(0.5f*a0.x, 0.5f*b0.x), mk2(0.5f*a0.y, 0.5f*b0.y), mk2(0.5f*a0.z, 0.5f*b0.z), u);
            g_u2<8>(V, u);
            make_u2(mk2(0.5f*a0.w, 0.5f*b0.w), mk2(0.5f*a1.x, 0.5f*b1.x), mk2(0.5f*a1.y, 0.5f*b1.y), u);
            g_u2<4>(V, u);
            make_u2(mk2(0.5f*a1.z, 0.5f*b1.z), mk2(0.5f*a1.w, 0.5f*b1.w), mk2(0.5f*a2.x, 0.5f*b2.x), u);
            g_u2<2>(V, u);
            make_u2(mk2(0.5f*a2.y, 0.5f*b2.y), mk2(0.5f*a2.z, 0.5f*b2.z), mk2(0.5f*a2.w, 0.5f*b2.w), u);
            g_u2<1>(V, u);
            // load group 2: CRX params (16 floats live)
            const float4 a3 = p4A[5*L+3], a4 = p4A[5*L+4];
            const float4 b3 = p4B[5*L+3], b4 = p4B[5*L+4];
            v2 sc[2];
            fsc2(mk2(0.5f*a3.x, 0.5f*b3.x), sc); g_crx_pre<8, 4>(V, sc[0], sc[1]);
            fsc2(mk2(0.5f*a3.y, 0.5f*b3.y), sc); g_crx_pre<4, 2>(V, sc[0], sc[1]);
            fsc2(mk2(0.5f*a3.z, 0.5f*b3.z), sc); g_crx_pre<2, 1>(V, sc[0], sc[1]);
            fsc2(mk2(0.5f*a3.w, 0.5f*b3.w), sc); g_crx_pre<1, 8>(V, sc[0], sc[1]);
            fsc2(mk2(0.5f*a4.x, 0.5f*b4.x), sc); g_crx_pre<1, 2>(V, sc[0], sc[1]);
            fsc2(mk2(0.5f*a4.y, 0.5f*b4.y), sc); g_crx_pre<2, 4>(V, sc[0], sc[1]);
            fsc2(mk2(0.5f*a4.z, 0.5f*b4.z), sc); g_crx_pre<4, 8>(V, sc[0], sc[1]);
            fsc2(mk2(0.5f*a4.w, 0.5f*b4.w), sc); g_crx_pre<8, 1>(V, sc[0], sc[1]);
        }

        // scale by each slot's LCU coefficient (0 for dead slot-B lanes)
        #pragma unroll
        for (int i = 0; i < 16; ++i) {
            v2 r = V[i], im = V[16 + i];
            V[i]      = FMA2(-im, ci_, r * cr_);
            V[16 + i] = FMA2( im, cr_, r * ci_);
        }

        // collapse the two timestep slots, then reduce across lanes
        float S[32];
        #pragma unroll
        for (int i = 0; i < 32; ++i) S[i] = V[i].x + V[i].y;

        rstep<0, 16>(S, lane);
        rstep<1, 8>(S, lane);
        rstep<2, 4>(S, lane);
        rstep<3, 2>(S, lane);
        rstep<4, 1>(S, lane);
        float tot = S[0] + __shfl_xor(S[0], 32, 64);
        if (lane < 32) s_red[wv][vidx] = tot;

        __syncthreads();
        if (tid < 32) {
            float r = s_red[0][tid] + s_red[1][tid];
            s_w[tid] = r;
            s_acc[tid] += poly[k] * r;
        }
        __syncthreads();
    }

    // ---- finalize on wave 0, lane-per-amplitude (verified round 2) ----
    if (tid < 16) {
        const int l = tid;
        float l1 = fabsf(poly[0]) + fabsf(poly[1]) + fabsf(poly[2]) + fabsf(poly[3]);
        float inv = 1.f / l1;
        float ar = s_acc[l] * inv, ai = s_acc[16 + l] * inv;
        float n2 = ar * ar + ai * ai;
        #pragma unroll
        for (int o = 1; o < 16; o <<= 1) n2 += __shfl_xor(n2, o, 64);
        float sc = 1.f / (sqrtf(n2) + 1e-9f);
        ar *= sc; ai *= sc;

        float s, c, pr, pi, se, ce, t0;
        #pragma unroll
        for (int w = 0; w < 4; ++w) {
            const int BIT = 8 >> w;
            fsc(0.5f * qff[3 * w + 0], s, c);            // RX
            pr = __shfl_xor(ar, BIT, 64); pi = __shfl_xor(ai, BIT, 64);
            t0 = c * ar + s * pi; ai = c * ai - s * pr; ar = t0;
            fsc(0.5f * qff[3 * w + 1], s, c);            // RY
            pr = __shfl_xor(ar, BIT, 64); pi = __shfl_xor(ai, BIT, 64);
            se = (l & BIT) ? s : -s;
            t0 = c * ar + se * pr; ai = c * ai + se * pi; ar = t0;
            fsc(0.5f * qff[3 * w + 2], s, c);            // RZ
            se = (l & BIT) ? s : -s;
            t0 = c * ar - se * ai; ai = c * ai + se * ar; ar = t0;
        }
        #define CRXF(CB, TB, hp) { fsc(0.5f * (hp), s, c);                        \
            pr = __shfl_xor(ar, TB, 64); pi = __shfl_xor(ai, TB, 64);             \
            ce = (l & CB) ? c : 1.f; se = (l & CB) ? s : 0.f;                     \
            t0 = ce * ar + se * pi; ai = ce * ai - se * pr; ar = t0; }
        CRXF(8, 4, qff[12]) CRXF(4, 2, qff[13]) CRXF(2, 1, qff[14]) CRXF(1, 8, qff[15])
        CRXF(1, 2, qff[16]) CRXF(2, 4, qff[17]) CRXF(4, 8, qff[18]) CRXF(8, 1, qff[19])
        #undef CRXF

        float* o = out + (size_t)b * 12;
        #pragma unroll
        for (int w = 0; w < 4; ++w) {
            const int BIT = 8 >> w;
            pr = __shfl_xor(ar, BIT, 64); pi = __shfl_xor(ai, BIT, 64);
            float m = (l & BIT) ? 0.f : 1.f;
            float X = m * 2.f * (ar * pr + ai * pi);
            float Y = m * 2.f * (ar * pi - ai * pr);
            float Z = m * (ar * ar + ai * ai - pr * pr - pi * pi);
            #pragma unroll
            for (int of = 1; of < 16; of <<= 1) {
                X += __shfl_xor(X, of, 64);
                Y += __shfl_xor(Y, of, 64);
                Z += __shfl_xor(Z, of, 64);
            }
            if (l == 0) { o[w] = X; o[4 + w] = Y; o[8 + w] = Z; }
        }
    }
}

extern "C" void kernel_launch(void* const* d_in, const int* in_sizes, int n_in,
                              void* d_out, int out_size, void* d_ws, size_t ws_size,
                              hipStream_t stream) {
    const float* tp   = (const float*)d_in[0];
    const float* poly = (const float*)d_in[1];
    const float* mixr = (const float*)d_in[2];
    const float* mixi = (const float*)d_in[3];
    const float* qff  = (const float*)d_in[4];
    float* out = (float*)d_out;
    const int B = in_sizes[0] / (TSTEPS * NROTS);   // 2048
    qac_kernel<<<dim3(B), dim3(BLK), 0, stream>>>(tp, poly, mixr, mixi, qff, out);
}

// Round 5
// 143.107 us; speedup vs baseline: 1.5596x; 1.3709x over previous
//
#include <hip/hip_runtime.h>
#include <math.h>

#define TSTEPS 200
#define NROTS  40      // 5*NQ*NL params per timestep circuit (2 layers)
#define BLK    128     // 2 waves; each thread simulates TWO timesteps (packed fp32)
#define DEG    3

// ---- packed float2 (maps to v_pk_*_f32 on gfx950) ----
typedef float v2 __attribute__((ext_vector_type(2)));

__device__ __forceinline__ v2 mk2(float a, float b) { v2 r; r.x = a; r.y = b; return r; }

#if __has_builtin(__builtin_elementwise_fma)
#define FMA2(a, b, c) __builtin_elementwise_fma((a), (b), (c))
#else
__device__ __forceinline__ v2 FMA2(v2 a, v2 b, v2 c) {
#pragma clang fp contract(fast)
    return a * b + c;
}
#endif

// Launder a v2 through an empty asm: pins the value into VGPRs and makes it
// opaque, so the scheduler/RA CANNOT rematerialize (recompute) it inside the
// k-loop. This is the anti-remat fix for round 1's 2.3x instruction bloat.
// (Bitcast to double: 64-bit scalar is a safe "+v" operand on AMDGPU.)
__device__ __forceinline__ void keep(v2& x) {
    double d = __builtin_bit_cast(double, x);
    asm volatile("" : "+v"(d));
    x = __builtin_bit_cast(v2, d);
}

__device__ __forceinline__ v2 sin2(v2 h) { return mk2(__sinf(h.x), __sinf(h.y)); }
__device__ __forceinline__ v2 cos2(v2 h) { return mk2(__cosf(h.x), __cosf(h.y)); }

__device__ __forceinline__ void fsc(float h, float& s, float& c) {
    s = __sinf(h); c = __cosf(h);
}

// Fused U = RZ(h3)*RY(h2)*RX(h1); only u00,u01 needed (u11=conj(u00), u10=-conj(u01)).
// Algebra verified in earlier rounds; element-wise over the 2 timestep slots.
__device__ __forceinline__ void make_u2(v2 h1, v2 h2, v2 h3, v2* u) {
    v2 s1 = sin2(h1), c1 = cos2(h1);
    v2 s2 = sin2(h2), c2 = cos2(h2);
    v2 s3 = sin2(h3), c3 = cos2(h3);
    v2 A = c1 * c2, Bv = s1 * s2, C = c1 * s2, D = s1 * c2;
    u[0] = FMA2(s3, Bv, c3 * A);        //  c3*A + s3*Bv
    u[1] = FMA2(-s3, A, c3 * Bv);       //  c3*Bv - s3*A
    u[2] = -FMA2(s3, D, c3 * C);        // -(c3*C + s3*D)
    u[3] = FMA2(-c3, D, s3 * C);        //  s3*C - c3*D
}

__device__ __forceinline__ void fsc2(v2 h, v2* sc) { sc[0] = sin2(h); sc[1] = cos2(h); }

// Planar state: V[0..15] = real amps, V[16..31] = imag; each v2 packs 2 timesteps.
// Wire w <-> bit (8>>w). Gate formulas verified; explicit fma chains. The 8
// (p,q) pairs per gate are independent -> ample ILP at low occupancy.
template<int BIT>
__device__ __forceinline__ void g_u2(v2* V, const v2* u) {
    const v2 u00r = u[0], u00i = u[1], u01r = u[2], u01i = u[3];
    #pragma unroll
    for (int p = 0; p < 16; ++p) {
        if (p & BIT) continue;
        const int q = p | BIT;
        v2 a0r = V[p], a0i = V[16 + p], a1r = V[q], a1i = V[16 + q];
        v2 t0 = u00r * a0r;
        t0 = FMA2(-u00i, a0i, t0);
        t0 = FMA2( u01r, a1r, t0);
        t0 = FMA2(-u01i, a1i, t0);
        v2 t1 = u00r * a0i;
        t1 = FMA2( u00i, a0r, t1);
        t1 = FMA2( u01r, a1i, t1);
        t1 = FMA2( u01i, a1r, t1);
        v2 t2 = u00r * a1r;
        t2 = FMA2( u00i, a1i, t2);
        t2 = FMA2(-u01r, a0r, t2);
        t2 = FMA2(-u01i, a0i, t2);
        v2 t3 = u00r * a1i;
        t3 = FMA2(-u00i, a1r, t3);
        t3 = FMA2(-u01r, a0i, t3);
        t3 = FMA2( u01i, a0r, t3);
        V[p] = t0; V[16 + p] = t1; V[q] = t2; V[16 + q] = t3;
    }
}

template<int CBIT, int TBIT>
__device__ __forceinline__ void g_crx_pre(v2* V, v2 s, v2 c) {
    #pragma unroll
    for (int p = 0; p < 16; ++p) {
        if (!(p & CBIT) || (p & TBIT)) continue;   // control=1, target=0 rows
        const int q = p | TBIT;
        v2 a0r = V[p], a0i = V[16 + p], a1r = V[q], a1i = V[16 + q];
        V[p]      = FMA2( s, a1i, c * a0r);
        V[16 + p] = FMA2(-s, a1r, c * a0i);
        V[q]      = FMA2( s, a0i, c * a1r);
        V[16 + q] = FMA2(-s, a0r, c * a1i);
    }
}

__device__ __forceinline__ void apply_layer_pre(v2* V, const v2 (&u)[4][4],
                                                const v2 (&cs)[8][2]) {
    g_u2<8>(V, u[0]); g_u2<4>(V, u[1]); g_u2<2>(V, u[2]); g_u2<1>(V, u[3]);
    g_crx_pre<8, 4>(V, cs[0][0], cs[0][1]);
    g_crx_pre<4, 2>(V, cs[1][0], cs[1][1]);
    g_crx_pre<2, 1>(V, cs[2][0], cs[2][1]);
    g_crx_pre<1, 8>(V, cs[3][0], cs[3][1]);
    g_crx_pre<1, 2>(V, cs[4][0], cs[4][1]);
    g_crx_pre<2, 4>(V, cs[5][0], cs[5][1]);
    g_crx_pre<4, 8>(V, cs[6][0], cs[6][1]);
    g_crx_pre<8, 1>(V, cs[7][0], cs[7][1]);
}

// Reduce-scatter halving step (scalar; slots already summed).
template<int S, int HALF>
__device__ __forceinline__ void rstep(float* V, int lane) {
    const bool hi = (lane >> S) & 1;
    #pragma unroll
    for (int j = 0; j < HALF; ++j) {
        float send = hi ? V[j] : V[j + HALF];
        float keep = hi ? V[j + HALF] : V[j];
        V[j] = keep + __shfl_xor(send, 1 << S, 64);
    }
}

// One block per batch element. Thread t simulates timesteps {t, t+128} packed.
// __launch_bounds__(128,2): VGPR cap 256 -> room for the ~180-reg natural live
// set (tables 96 + state 64 + temps), so NO spill and NO remat. Residency is
// 2 waves/SIMD; round 0 showed ~2.6 waves/SIMD sustains >90% issue given ILP.
extern "C" __global__ void __launch_bounds__(BLK, 2)
qac_kernel(const float* __restrict__ tp,    // (B, T, NROTS)
           const float* __restrict__ poly,  // (DEG+1,)
           const float* __restrict__ mixr,  // (T,)
           const float* __restrict__ mixi,  // (T,)
           const float* __restrict__ qff,   // (20,)
           float* __restrict__ out)         // (B, 12)
{
    __shared__ float s_red[2][32];   // per-wave reduced values (value-indexed)
    __shared__ float s_w[32];        // work vector  (0..15 re, 16..31 im)
    __shared__ float s_acc[32];      // QSVT accumulator, same layout

    const int b    = blockIdx.x;
    const int tid  = threadIdx.x;
    const int lane = tid & 63;
    const int wv   = tid >> 6;

    if (tid < 32) {
        s_w[tid]   = (tid == 0) ? 1.f : 0.f;
        s_acc[tid] = (tid == 0) ? poly[0] : 0.f;
    }

    // slot A = timestep tid (always < 200); slot B = timestep tid+128 (clamped, coeff 0)
    const bool vB = (tid + BLK) < TSTEPS;
    const int  tB = vB ? (tid + BLK) : (TSTEPS - 1);
    v2 cr_ = mk2(mixr[tid], vB ? mixr[tid + BLK] : 0.f);
    v2 ci_ = mk2(mixi[tid], vB ? mixi[tid + BLK] : 0.f);

    const float4* p4A = (const float4*)(tp + (size_t)b * (TSTEPS * NROTS) + tid * NROTS);
    const float4* p4B = (const float4*)(tp + (size_t)b * (TSTEPS * NROTS) + tB * NROTS);

    // ---- hoist ALL trig out of the QSVT loop (params identical each pass) ----
    v2 tu[2][4][4];   // [layer][wire][u00r,u00i,u01r,u01i]
    v2 tc[2][8][2];   // [layer][crx gate][s,c]
    #pragma unroll
    for (int L = 0; L < 2; ++L) {
        float4 a0 = p4A[5*L+0], a1 = p4A[5*L+1], a2 = p4A[5*L+2], a3 = p4A[5*L+3], a4 = p4A[5*L+4];
        float4 b0 = p4B[5*L+0], b1 = p4B[5*L+1], b2 = p4B[5*L+2], b3 = p4B[5*L+3], b4 = p4B[5*L+4];
        make_u2(mk2(0.5f*a0.x, 0.5f*b0.x), mk2(0.5f*a0.y, 0.5f*b0.y), mk2(0.5f*a0.z, 0.5f*b0.z), tu[L][0]);
        make_u2(mk2(0.5f*a0.w, 0.5f*b0.w), mk2(0.5f*a1.x, 0.5f*b1.x), mk2(0.5f*a1.y, 0.5f*b1.y), tu[L][1]);
        make_u2(mk2(0.5f*a1.z, 0.5f*b1.z), mk2(0.5f*a1.w, 0.5f*b1.w), mk2(0.5f*a2.x, 0.5f*b2.x), tu[L][2]);
        make_u2(mk2(0.5f*a2.y, 0.5f*b2.y), mk2(0.5f*a2.z, 0.5f*b2.z), mk2(0.5f*a2.w, 0.5f*b2.w), tu[L][3]);
        fsc2(mk2(0.5f*a3.x, 0.5f*b3.x), tc[L][0]);
        fsc2(mk2(0.5f*a3.y, 0.5f*b3.y), tc[L][1]);
        fsc2(mk2(0.5f*a3.z, 0.5f*b3.z), tc[L][2]);
        fsc2(mk2(0.5f*a3.w, 0.5f*b3.w), tc[L][3]);
        fsc2(mk2(0.5f*a4.x, 0.5f*b4.x), tc[L][4]);
        fsc2(mk2(0.5f*a4.y, 0.5f*b4.y), tc[L][5]);
        fsc2(mk2(0.5f*a4.z, 0.5f*b4.z), tc[L][6]);
        fsc2(mk2(0.5f*a4.w, 0.5f*b4.w), tc[L][7]);
    }

    // Pin every table value into registers (anti-remat). Zero instructions.
    #pragma unroll
    for (int L = 0; L < 2; ++L) {
        #pragma unroll
        for (int w = 0; w < 4; ++w) {
            #pragma unroll
            for (int j = 0; j < 4; ++j) keep(tu[L][w][j]);
        }
        #pragma unroll
        for (int g = 0; g < 8; ++g) { keep(tc[L][g][0]); keep(tc[L][g][1]); }
    }

    // reduce-scatter destination: value index bitrev5(lane&31) (verified round 2)
    const int vidx = ((lane & 1) << 4) | ((lane & 2) << 2) | (lane & 4) |
                     ((lane & 8) >> 2) | ((lane & 16) >> 4);

    __syncthreads();

    #pragma unroll 1
    for (int k = 1; k <= DEG; ++k) {
        v2 V[32];
        #pragma unroll
        for (int i = 0; i < 32; ++i) { float t = s_w[i]; V[i] = mk2(t, t); }

        apply_layer_pre(V, tu[0], tc[0]);
        apply_layer_pre(V, tu[1], tc[1]);

        // scale by each slot's LCU coefficient (0 for dead slot-B lanes)
        #pragma unroll
        for (int i = 0; i < 16; ++i) {
            v2 r = V[i], im = V[16 + i];
            V[i]      = FMA2(-im, ci_, r * cr_);
            V[16 + i] = FMA2( im, cr_, r * ci_);
        }

        // collapse the two timestep slots, then reduce across lanes
        float S[32];
        #pragma unroll
        for (int i = 0; i < 32; ++i) S[i] = V[i].x + V[i].y;

        rstep<0, 16>(S, lane);
        rstep<1, 8>(S, lane);
        rstep<2, 4>(S, lane);
        rstep<3, 2>(S, lane);
        rstep<4, 1>(S, lane);
        float tot = S[0] + __shfl_xor(S[0], 32, 64);
        if (lane < 32) s_red[wv][vidx] = tot;

        __syncthreads();
        if (tid < 32) {
            float r = s_red[0][tid] + s_red[1][tid];
            s_w[tid] = r;
            s_acc[tid] += poly[k] * r;
        }
        __syncthreads();
    }

    // ---- finalize on wave 0, lane-per-amplitude (verified round 2) ----
    if (tid < 16) {
        const int l = tid;
        float l1 = fabsf(poly[0]) + fabsf(poly[1]) + fabsf(poly[2]) + fabsf(poly[3]);
        float inv = 1.f / l1;
        float ar = s_acc[l] * inv, ai = s_acc[16 + l] * inv;
        float n2 = ar * ar + ai * ai;
        #pragma unroll
        for (int o = 1; o < 16; o <<= 1) n2 += __shfl_xor(n2, o, 64);
        float sc = 1.f / (sqrtf(n2) + 1e-9f);
        ar *= sc; ai *= sc;

        float s, c, pr, pi, se, ce, t0;
        #pragma unroll
        for (int w = 0; w < 4; ++w) {
            const int BIT = 8 >> w;
            fsc(0.5f * qff[3 * w + 0], s, c);            // RX
            pr = __shfl_xor(ar, BIT, 64); pi = __shfl_xor(ai, BIT, 64);
            t0 = c * ar + s * pi; ai = c * ai - s * pr; ar = t0;
            fsc(0.5f * qff[3 * w + 1], s, c);            // RY
            pr = __shfl_xor(ar, BIT, 64); pi = __shfl_xor(ai, BIT, 64);
            se = (l & BIT) ? s : -s;
            t0 = c * ar + se * pr; ai = c * ai + se * pi; ar = t0;
            fsc(0.5f * qff[3 * w + 2], s, c);            // RZ
            se = (l & BIT) ? s : -s;
            t0 = c * ar - se * ai; ai = c * ai + se * ar; ar = t0;
        }
        #define CRXF(CB, TB, hp) { fsc(0.5f * (hp), s, c);                        \
            pr = __shfl_xor(ar, TB, 64); pi = __shfl_xor(ai, TB, 64);             \
            ce = (l & CB) ? c : 1.f; se = (l & CB) ? s : 0.f;                     \
            t0 = ce * ar + se * pi; ai = ce * ai - se * pr; ar = t0; }
        CRXF(8, 4, qff[12]) CRXF(4, 2, qff[13]) CRXF(2, 1, qff[14]) CRXF(1, 8, qff[15])
        CRXF(1, 2, qff[16]) CRXF(2, 4, qff[17]) CRXF(4, 8, qff[18]) CRXF(8, 1, qff[19])
        #undef CRXF

        float* o = out + (size_t)b * 12;
        #pragma unroll
        for (int w = 0; w < 4; ++w) {
            const int BIT = 8 >> w;
            pr = __shfl_xor(ar, BIT, 64); pi = __shfl_xor(ai, BIT, 64);
            float m = (l & BIT) ? 0.f : 1.f;
            float X = m * 2.f * (ar * pr + ai * pi);
            float Y = m * 2.f * (ar * pi - ai * pr);
            float Z = m * (ar * ar + ai * ai - pr * pr - pi * pi);
            #pragma unroll
            for (int of = 1; of < 16; of <<= 1) {
                X += __shfl_xor(X, of, 64);
                Y += __shfl_xor(Y, of, 64);
                Z += __shfl_xor(Z, of, 64);
            }
            if (l == 0) { o[w] = X; o[4 + w] = Y; o[8 + w] = Z; }
        }
    }
}

extern "C" void kernel_launch(void* const* d_in, const int* in_sizes, int n_in,
                              void* d_out, int out_size, void* d_ws, size_t ws_size,
                              hipStream_t stream) {
    const float* tp   = (const float*)d_in[0];
    const float* poly = (const float*)d_in[1];
    const float* mixr = (const float*)d_in[2];
    const float* mixi = (const float*)d_in[3];
    const float* qff  = (const float*)d_in[4];
    float* out = (float*)d_out;
    const int B = in_sizes[0] / (TSTEPS * NROTS);   // 2048
    qac_kernel<<<dim3(B), dim3(BLK), 0, stream>>>(tp, poly, mixr, mixi, qff, out);
}